// Round 1
// baseline (594.833 us; speedup 1.0000x reference)
//
#include <hip/hip_runtime.h>

// B=8 S=512 D=768 H=256 C=32, G==H
// out[b,s,e,c] = biaff + lin, 8*512*512*32 fp32

typedef __bf16 bf16x8 __attribute__((ext_vector_type(8)));
typedef float f32x4 __attribute__((ext_vector_type(4)));

union BF8 { unsigned short s[8]; unsigned int u[4]; bf16x8 v; };

__device__ __forceinline__ unsigned short f2bf(float f) {
    unsigned u = __builtin_bit_cast(unsigned, f);
    u += 0x7fffu + ((u >> 16) & 1u);
    return (unsigned short)(u >> 16);
}
__device__ __forceinline__ float bf2f(unsigned short s) {
    unsigned u = ((unsigned)s) << 16;
    return __builtin_bit_cast(float, u);
}
__device__ __forceinline__ bf16x8 load_bf8(const unsigned short* p) {
    return __builtin_bit_cast(bf16x8, *reinterpret_cast<const uint4*>(p));
}

// ---------------- K0: Ut[c*256+g][h] = bf16(U[h][c*256+g]) --------------
// U viewed as (256 h, 8192 J) -> Ut (8192 J, 256 h), LDS 32x32 tile transpose
__global__ __launch_bounds__(256) void k0_ut(const float* __restrict__ U,
                                             unsigned short* __restrict__ Ut) {
    __shared__ float tile[32][33];
    int tx = threadIdx.x, ty = threadIdx.y;
    int J0 = blockIdx.x * 32, h0 = blockIdx.y * 32;
#pragma unroll
    for (int i = 0; i < 4; i++)
        tile[ty + 8 * i][tx] = U[(h0 + ty + 8 * i) * 8192 + J0 + tx];
    __syncthreads();
#pragma unroll
    for (int i = 0; i < 4; i++)
        Ut[(J0 + ty + 8 * i) * 256 + h0 + tx] = f2bf(tile[tx][ty + 8 * i]);
}

// ---------------- K1: Hs/He = bf16(seq @ W^T + bias) --------------------
// wave computes a 16(m=bs) x 16(n=h) tile; n_t<16 -> Hs, else He
__global__ __launch_bounds__(256) void k1_hs_he(
    const float* __restrict__ seq, const float* __restrict__ Ws_w,
    const float* __restrict__ Ws_b, const float* __restrict__ We_w,
    const float* __restrict__ We_b, unsigned short* __restrict__ Hs,
    unsigned short* __restrict__ He) {
    int wid = threadIdx.x >> 6, lane = threadIdx.x & 63;
    int t = lane & 15, q = lane >> 4;
    int wave_id = blockIdx.x * 4 + wid;     // 0..8191
    int m_t = wave_id >> 5;                 // 0..255
    int n_t = wave_id & 31;                 // 0..31
    int which = n_t >> 4;                   // 0=Hs 1=He
    int h0 = (n_t & 15) * 16;
    const float* Wm = which ? We_w : Ws_w;
    const float* bias = which ? We_b : Ws_b;
    unsigned short* outm = which ? He : Hs;

    const float* arow = seq + (size_t)(m_t * 16 + t) * 768;
    const float* brow = Wm + (size_t)(h0 + t) * 768;

    f32x4 acc = {0.f, 0.f, 0.f, 0.f};
#pragma unroll
    for (int kk = 0; kk < 24; kk++) {
        int k = kk * 32 + q * 8;
        float4 a0 = *(const float4*)(arow + k);
        float4 a1 = *(const float4*)(arow + k + 4);
        float4 b0 = *(const float4*)(brow + k);
        float4 b1 = *(const float4*)(brow + k + 4);
        BF8 a, b;
        a.s[0] = f2bf(a0.x); a.s[1] = f2bf(a0.y); a.s[2] = f2bf(a0.z); a.s[3] = f2bf(a0.w);
        a.s[4] = f2bf(a1.x); a.s[5] = f2bf(a1.y); a.s[6] = f2bf(a1.z); a.s[7] = f2bf(a1.w);
        b.s[0] = f2bf(b0.x); b.s[1] = f2bf(b0.y); b.s[2] = f2bf(b0.z); b.s[3] = f2bf(b0.w);
        b.s[4] = f2bf(b1.x); b.s[5] = f2bf(b1.y); b.s[6] = f2bf(b1.z); b.s[7] = f2bf(b1.w);
        acc = __builtin_amdgcn_mfma_f32_16x16x32_bf16(a.v, b.v, acc, 0, 0, 0);
    }
    float bv = bias[h0 + t];
#pragma unroll
    for (int r = 0; r < 4; r++) {
        int bs = m_t * 16 + q * 4 + r;
        outm[bs * 256 + h0 + t] = f2bf(acc[r] + bv);
    }
}

// ---------------- K2: linS[bs,c] = Hs.W_s^T ; linE[bs,c] = He.W_e^T + W_b
__global__ __launch_bounds__(256) void k2_lin(
    const unsigned short* __restrict__ Hs, const unsigned short* __restrict__ He,
    const float* __restrict__ W_w, const float* __restrict__ W_b,
    float* __restrict__ linS, float* __restrict__ linE) {
    int idx = blockIdx.x * 256 + threadIdx.x;  // 0..262143
    int c = idx & 31;
    int rowid = idx >> 5;        // 0..8191
    int which = rowid >> 12;     // 0 -> linS, 1 -> linE
    int bs = rowid & 4095;
    const unsigned short* Hrow = (which ? He : Hs) + bs * 256;
    const float* Wrow = W_w + c * 512 + which * 256;
    float acc = which ? W_b[c] : 0.f;
#pragma unroll 4
    for (int h8 = 0; h8 < 32; h8++) {
        BF8 hv;
        hv.v = load_bf8(Hrow + h8 * 8);
        float4 w0 = *(const float4*)(Wrow + h8 * 8);
        float4 w1 = *(const float4*)(Wrow + h8 * 8 + 4);
        acc += bf2f(hv.s[0]) * w0.x + bf2f(hv.s[1]) * w0.y + bf2f(hv.s[2]) * w0.z +
               bf2f(hv.s[3]) * w0.w + bf2f(hv.s[4]) * w1.x + bf2f(hv.s[5]) * w1.y +
               bf2f(hv.s[6]) * w1.z + bf2f(hv.s[7]) * w1.w;
    }
    (which ? linE : linS)[bs * 32 + c] = acc;
}

// ---------------- K3: T[bs][c][g] = bf16( sum_h Hs[bs,h] * Ut[c,g,h] ) --
// wave: 2 m-tiles (32 s) x one (c, g-half=128): 8 n-tiles, K=256 (8 steps)
__global__ __launch_bounds__(256) void k3_T(
    const unsigned short* __restrict__ Hs, const unsigned short* __restrict__ Ut,
    unsigned short* __restrict__ T) {
    int wid = threadIdx.x >> 6, lane = threadIdx.x & 63;
    int t = lane & 15, q = lane >> 4;
    int wave_id = blockIdx.x * 4 + wid;  // 0..8191
    int mb = wave_id >> 6;               // 0..127 (32 s each)
    int n_blk = wave_id & 63;            // c(32) x g-half(2)
    int c = n_blk >> 1;
    int g0 = (n_blk & 1) * 128;
    int s0 = mb * 32;

    bf16x8 afr[2][8];
#pragma unroll
    for (int mt = 0; mt < 2; mt++) {
        const unsigned short* arow = Hs + (s0 + mt * 16 + t) * 256 + q * 8;
#pragma unroll
        for (int kk = 0; kk < 8; kk++) afr[mt][kk] = load_bf8(arow + kk * 32);
    }
#pragma unroll 2
    for (int nt = 0; nt < 8; nt++) {
        const unsigned short* brow = Ut + (size_t)(c * 256 + g0 + nt * 16 + t) * 256 + q * 8;
        f32x4 acc0 = {0.f, 0.f, 0.f, 0.f}, acc1 = {0.f, 0.f, 0.f, 0.f};
#pragma unroll
        for (int kk = 0; kk < 8; kk++) {
            bf16x8 b = load_bf8(brow + kk * 32);
            acc0 = __builtin_amdgcn_mfma_f32_16x16x32_bf16(afr[0][kk], b, acc0, 0, 0, 0);
            acc1 = __builtin_amdgcn_mfma_f32_16x16x32_bf16(afr[1][kk], b, acc1, 0, 0, 0);
        }
        int g = g0 + nt * 16 + t;
#pragma unroll
        for (int r = 0; r < 4; r++) {
            int s_a = s0 + q * 4 + r;
            int s_b = s_a + 16;
            T[(size_t)(s_a * 32 + c) * 256 + g] = f2bf(acc0[r]);
            T[(size_t)(s_b * 32 + c) * 256 + g] = f2bf(acc1[r]);
        }
    }
}

// ---------------- K4: out[bs][e][c] = He[b] . T[bs]^T + linS + linE -----
// per fixed s: D[m=e][n=c], A=He rows(e x g), B^T=T[bs] rows(c x g).
// D lane layout: c = lane&15 (+16 per n-tile), e = e0 + q*4 + r
// -> each quad's store = 16 consecutive dwords (64B) in the (...,e,c) output.
__global__ __launch_bounds__(256) void k4_out(
    const unsigned short* __restrict__ T, const unsigned short* __restrict__ He,
    const float* __restrict__ linS, const float* __restrict__ linE,
    float* __restrict__ out) {
    int wid = threadIdx.x >> 6, lane = threadIdx.x & 63;
    int t = lane & 15, q = lane >> 4;
    int b = blockIdx.x >> 6;      // 0..7
    int s_grp = blockIdx.x & 63;  // 0..63 (8 s each; wave -> 2 s)
#pragma unroll 1
    for (int si = 0; si < 2; si++) {
        int s = s_grp * 8 + wid * 2 + si;
        int bs = b * 512 + s;
        bf16x8 bfr[2][8];  // T[bs] fragments, resident across e-loop
#pragma unroll
        for (int nt = 0; nt < 2; nt++) {
            const unsigned short* brow = T + (size_t)(bs * 32 + nt * 16 + t) * 256 + q * 8;
#pragma unroll
            for (int kk = 0; kk < 8; kk++) bfr[nt][kk] = load_bf8(brow + kk * 32);
        }
        float ls0 = linS[bs * 32 + t];
        float ls1 = linS[bs * 32 + 16 + t];
        float* orow = out + (size_t)bs * (512 * 32);
#pragma unroll 1
        for (int e_t = 0; e_t < 32; e_t++) {
            int e0 = e_t * 16;
            const unsigned short* arow = He + (size_t)(b * 512 + e0 + t) * 256 + q * 8;
            f32x4 acc0 = {0.f, 0.f, 0.f, 0.f}, acc1 = {0.f, 0.f, 0.f, 0.f};
#pragma unroll
            for (int kk = 0; kk < 8; kk++) {
                bf16x8 a = load_bf8(arow + kk * 32);
                acc0 = __builtin_amdgcn_mfma_f32_16x16x32_bf16(a, bfr[0][kk], acc0, 0, 0, 0);
                acc1 = __builtin_amdgcn_mfma_f32_16x16x32_bf16(a, bfr[1][kk], acc1, 0, 0, 0);
            }
#pragma unroll
            for (int r = 0; r < 4; r++) {
                int e = e0 + q * 4 + r;
                float le0 = linE[(b * 512 + e) * 32 + t];
                float le1 = linE[(b * 512 + e) * 32 + 16 + t];
                orow[e * 32 + t] = acc0[r] + ls0 + le0;
                orow[e * 32 + 16 + t] = acc1[r] + ls1 + le1;
            }
        }
    }
}

extern "C" void kernel_launch(void* const* d_in, const int* in_sizes, int n_in,
                              void* d_out, int out_size, void* d_ws, size_t ws_size,
                              hipStream_t stream) {
    const float* seq  = (const float*)d_in[0];
    const float* U    = (const float*)d_in[1];
    const float* W_w  = (const float*)d_in[2];
    const float* W_b  = (const float*)d_in[3];
    const float* Ws_w = (const float*)d_in[4];
    const float* Ws_b = (const float*)d_in[5];
    const float* We_w = (const float*)d_in[6];
    const float* We_b = (const float*)d_in[7];
    float* out = (float*)d_out;

    char* ws = (char*)d_ws;
    unsigned short* Hs = (unsigned short*)(ws);                     // 2 MB
    unsigned short* He = (unsigned short*)(ws + (2ull << 20));      // 2 MB
    unsigned short* Ut = (unsigned short*)(ws + (4ull << 20));      // 4 MB
    float* linS = (float*)(ws + (8ull << 20));                      // 0.5 MB
    float* linE = (float*)(ws + (8ull << 20) + (1ull << 19));       // 0.5 MB
    unsigned short* T = (unsigned short*)(ws + (9ull << 20));       // 64 MB

    k0_ut<<<dim3(256, 8), dim3(32, 8), 0, stream>>>(U, Ut);
    k1_hs_he<<<2048, 256, 0, stream>>>(seq, Ws_w, Ws_b, We_w, We_b, Hs, He);
    k2_lin<<<1024, 256, 0, stream>>>(Hs, He, W_w, W_b, linS, linE);
    k3_T<<<2048, 256, 0, stream>>>(Hs, Ut, T);
    k4_out<<<512, 256, 0, stream>>>(T, He, linS, linE, out);
}

// Round 2
// 540.933 us; speedup vs baseline: 1.0996x; 1.0996x over previous
//
#include <hip/hip_runtime.h>

// B=8 S=512 D=768 H=256 C=32, G==H
// out[b,s,e,c] = biaff + lin, 8*512*512*32 fp32

typedef __bf16 bf16x8 __attribute__((ext_vector_type(8)));
typedef float f32x4 __attribute__((ext_vector_type(4)));

union BF8 { unsigned short s[8]; unsigned int u[4]; bf16x8 v; };

__device__ __forceinline__ unsigned short f2bf(float f) {
    unsigned u = __builtin_bit_cast(unsigned, f);
    u += 0x7fffu + ((u >> 16) & 1u);
    return (unsigned short)(u >> 16);
}
__device__ __forceinline__ float bf2f(unsigned short s) {
    unsigned u = ((unsigned)s) << 16;
    return __builtin_bit_cast(float, u);
}
__device__ __forceinline__ bf16x8 load_bf8(const unsigned short* p) {
    return __builtin_bit_cast(bf16x8, *reinterpret_cast<const uint4*>(p));
}
__device__ __forceinline__ ushort4 pack4(float4 v) {
    ushort4 r;
    r.x = f2bf(v.x); r.y = f2bf(v.y); r.z = f2bf(v.z); r.w = f2bf(v.w);
    return r;
}

// ---------------- KP: fp32 -> bf16 pre-convert: seqb, Wcat --------------
// seq: 786432 float4; Ws_w: 49152 float4; We_w: 49152 float4
__global__ __launch_bounds__(256) void kp_conv(
    const float* __restrict__ seq, const float* __restrict__ Ws_w,
    const float* __restrict__ We_w, unsigned short* __restrict__ seqb,
    unsigned short* __restrict__ Wcat) {
    int i = blockIdx.x * 256 + threadIdx.x;  // < 884736
    if (i < 786432) {
        float4 v = ((const float4*)seq)[i];
        ((ushort4*)seqb)[i] = pack4(v);
    } else {
        int j = i - 786432;  // 0..98303
        float4 v = (j < 49152) ? ((const float4*)Ws_w)[j]
                               : ((const float4*)We_w)[j - 49152];
        ((ushort4*)Wcat)[j] = pack4(v);
    }
}

// ---------------- K0: Ut[c*256+g][h] = bf16(U[h][c*256+g]) --------------
__global__ __launch_bounds__(256) void k0_ut(const float* __restrict__ U,
                                             unsigned short* __restrict__ Ut) {
    __shared__ float tile[32][33];
    int tx = threadIdx.x, ty = threadIdx.y;
    int J0 = blockIdx.x * 32, h0 = blockIdx.y * 32;
#pragma unroll
    for (int i = 0; i < 4; i++)
        tile[ty + 8 * i][tx] = U[(h0 + ty + 8 * i) * 8192 + J0 + tx];
    __syncthreads();
#pragma unroll
    for (int i = 0; i < 4; i++)
        Ut[(J0 + ty + 8 * i) * 256 + h0 + tx] = f2bf(tile[tx][ty + 8 * i]);
}

// ---------------- K1: Hs/He = bf16(seqb @ Wcat^T + bias), 32x32/wave ----
__global__ __launch_bounds__(256) void k1_hs_he(
    const unsigned short* __restrict__ seqb, const unsigned short* __restrict__ Wcat,
    const float* __restrict__ Ws_b, const float* __restrict__ We_b,
    unsigned short* __restrict__ Hs, unsigned short* __restrict__ He) {
    int wid = threadIdx.x >> 6, lane = threadIdx.x & 63;
    int t = lane & 15, q = lane >> 4;
    int wave_id = blockIdx.x * 4 + wid;  // 0..2047
    int m0 = (wave_id >> 4) * 32;        // 0..4064
    int n0 = (wave_id & 15) * 32;        // 0..480

    const unsigned short* a0 = seqb + (size_t)(m0 + t) * 768;
    const unsigned short* a1 = seqb + (size_t)(m0 + 16 + t) * 768;
    const unsigned short* b0 = Wcat + (size_t)(n0 + t) * 768;
    const unsigned short* b1 = Wcat + (size_t)(n0 + 16 + t) * 768;

    f32x4 acc[2][2];
#pragma unroll
    for (int i = 0; i < 2; i++)
#pragma unroll
        for (int j = 0; j < 2; j++) acc[i][j] = {0.f, 0.f, 0.f, 0.f};

#pragma unroll 4
    for (int kk = 0; kk < 24; kk++) {
        int k = kk * 32 + q * 8;
        bf16x8 af0 = load_bf8(a0 + k);
        bf16x8 af1 = load_bf8(a1 + k);
        bf16x8 bf0 = load_bf8(b0 + k);
        bf16x8 bf1 = load_bf8(b1 + k);
        acc[0][0] = __builtin_amdgcn_mfma_f32_16x16x32_bf16(af0, bf0, acc[0][0], 0, 0, 0);
        acc[0][1] = __builtin_amdgcn_mfma_f32_16x16x32_bf16(af0, bf1, acc[0][1], 0, 0, 0);
        acc[1][0] = __builtin_amdgcn_mfma_f32_16x16x32_bf16(af1, bf0, acc[1][0], 0, 0, 0);
        acc[1][1] = __builtin_amdgcn_mfma_f32_16x16x32_bf16(af1, bf1, acc[1][1], 0, 0, 0);
    }
#pragma unroll
    for (int nt = 0; nt < 2; nt++) {
        int col = n0 + nt * 16 + t;
        float bv;
        unsigned short* dst;
        int c2;
        if (col < 256) { bv = Ws_b[col]; dst = Hs; c2 = col; }
        else           { bv = We_b[col - 256]; dst = He; c2 = col - 256; }
#pragma unroll
        for (int mt = 0; mt < 2; mt++)
#pragma unroll
            for (int r = 0; r < 4; r++) {
                int row = m0 + mt * 16 + q * 4 + r;
                dst[row * 256 + c2] = f2bf(acc[mt][nt][r] + bv);
            }
    }
}

// ---------------- K2: linS[bs,c] = Hs.W_s^T ; linE[bs,c] = He.W_e^T + W_b
__global__ __launch_bounds__(256) void k2_lin(
    const unsigned short* __restrict__ Hs, const unsigned short* __restrict__ He,
    const float* __restrict__ W_w, const float* __restrict__ W_b,
    float* __restrict__ linS, float* __restrict__ linE) {
    int idx = blockIdx.x * 256 + threadIdx.x;  // 0..262143
    int c = idx & 31;
    int rowid = idx >> 5;
    int which = rowid >> 12;
    int bs = rowid & 4095;
    const unsigned short* Hrow = (which ? He : Hs) + bs * 256;
    const float* Wrow = W_w + c * 512 + which * 256;
    float acc = which ? W_b[c] : 0.f;
#pragma unroll 4
    for (int h8 = 0; h8 < 32; h8++) {
        BF8 hv;
        hv.v = load_bf8(Hrow + h8 * 8);
        float4 w0 = *(const float4*)(Wrow + h8 * 8);
        float4 w1 = *(const float4*)(Wrow + h8 * 8 + 4);
        acc += bf2f(hv.s[0]) * w0.x + bf2f(hv.s[1]) * w0.y + bf2f(hv.s[2]) * w0.z +
               bf2f(hv.s[3]) * w0.w + bf2f(hv.s[4]) * w1.x + bf2f(hv.s[5]) * w1.y +
               bf2f(hv.s[6]) * w1.z + bf2f(hv.s[7]) * w1.w;
    }
    (which ? linE : linS)[bs * 32 + c] = acc;
}

// ---------------- K3: T[bs][c][g] = bf16( sum_h Hs[bs,h] * Ut[c,g,h] ) --
// XCD swizzle: n_blk = blockIdx&63 -> XCD = n_blk&7; per-XCD Ut slice 512KB
__global__ __launch_bounds__(256) void k3_T(
    const unsigned short* __restrict__ Hs, const unsigned short* __restrict__ Ut,
    unsigned short* __restrict__ T) {
    int wid = threadIdx.x >> 6, lane = threadIdx.x & 63;
    int t = lane & 15, q = lane >> 4;
    int n_blk = blockIdx.x & 63;            // fixed per block
    int mb = (blockIdx.x >> 6) * 4 + wid;   // 0..127
    int c = n_blk >> 1;
    int g0 = (n_blk & 1) * 128;
    int s0 = mb * 32;

    bf16x8 afr[2][8];
#pragma unroll
    for (int mt = 0; mt < 2; mt++) {
        const unsigned short* arow = Hs + (s0 + mt * 16 + t) * 256 + q * 8;
#pragma unroll
        for (int kk = 0; kk < 8; kk++) afr[mt][kk] = load_bf8(arow + kk * 32);
    }
#pragma unroll 2
    for (int nt = 0; nt < 8; nt++) {
        const unsigned short* brow = Ut + (size_t)(c * 256 + g0 + nt * 16 + t) * 256 + q * 8;
        f32x4 acc0 = {0.f, 0.f, 0.f, 0.f}, acc1 = {0.f, 0.f, 0.f, 0.f};
#pragma unroll
        for (int kk = 0; kk < 8; kk++) {
            bf16x8 b = load_bf8(brow + kk * 32);
            acc0 = __builtin_amdgcn_mfma_f32_16x16x32_bf16(afr[0][kk], b, acc0, 0, 0, 0);
            acc1 = __builtin_amdgcn_mfma_f32_16x16x32_bf16(afr[1][kk], b, acc1, 0, 0, 0);
        }
        int g = g0 + nt * 16 + t;
#pragma unroll
        for (int r = 0; r < 4; r++) {
            int s_a = s0 + q * 4 + r;
            int s_b = s_a + 16;
            T[(size_t)(s_a * 32 + c) * 256 + g] = f2bf(acc0[r]);
            T[(size_t)(s_b * 32 + c) * 256 + g] = f2bf(acc1[r]);
        }
    }
}

// ---------------- K4: out[bs][e][c] = He[b] . T[bs]^T + linS + linE -----
// XCD swizzle: b = blockIdx&7 -> He[b] (256KB) resident per XCD L2.
// 1024 blocks, wave = 1 s -> 16 waves/CU.
__global__ __launch_bounds__(256) void k4_out(
    const unsigned short* __restrict__ T, const unsigned short* __restrict__ He,
    const float* __restrict__ linS, const float* __restrict__ linE,
    float* __restrict__ out) {
    int wid = threadIdx.x >> 6, lane = threadIdx.x & 63;
    int t = lane & 15, q = lane >> 4;
    int b = blockIdx.x & 7;
    int s = (blockIdx.x >> 3) * 4 + wid;  // 0..511
    int bs = b * 512 + s;

    bf16x8 bfr[2][8];  // T[bs] fragments, resident across e-loop
#pragma unroll
    for (int nt = 0; nt < 2; nt++) {
        const unsigned short* brow = T + (size_t)(bs * 32 + nt * 16 + t) * 256 + q * 8;
#pragma unroll
        for (int kk = 0; kk < 8; kk++) bfr[nt][kk] = load_bf8(brow + kk * 32);
    }
    float ls0 = linS[bs * 32 + t];
    float ls1 = linS[bs * 32 + 16 + t];
    float* orow = out + (size_t)bs * (512 * 32);
#pragma unroll 2
    for (int e_t = 0; e_t < 32; e_t++) {
        int e0 = e_t * 16;
        const unsigned short* arow = He + (size_t)(b * 512 + e0 + t) * 256 + q * 8;
        f32x4 acc0 = {0.f, 0.f, 0.f, 0.f}, acc1 = {0.f, 0.f, 0.f, 0.f};
#pragma unroll
        for (int kk = 0; kk < 8; kk++) {
            bf16x8 a = load_bf8(arow + kk * 32);
            acc0 = __builtin_amdgcn_mfma_f32_16x16x32_bf16(a, bfr[0][kk], acc0, 0, 0, 0);
            acc1 = __builtin_amdgcn_mfma_f32_16x16x32_bf16(a, bfr[1][kk], acc1, 0, 0, 0);
        }
#pragma unroll
        for (int r = 0; r < 4; r++) {
            int e = e0 + q * 4 + r;
            float le0 = linE[(b * 512 + e) * 32 + t];
            float le1 = linE[(b * 512 + e) * 32 + 16 + t];
            orow[e * 32 + t] = acc0[r] + ls0 + le0;
            orow[e * 32 + 16 + t] = acc1[r] + ls1 + le1;
        }
    }
}

extern "C" void kernel_launch(void* const* d_in, const int* in_sizes, int n_in,
                              void* d_out, int out_size, void* d_ws, size_t ws_size,
                              hipStream_t stream) {
    const float* seq  = (const float*)d_in[0];
    const float* U    = (const float*)d_in[1];
    const float* W_w  = (const float*)d_in[2];
    const float* W_b  = (const float*)d_in[3];
    const float* Ws_w = (const float*)d_in[4];
    const float* Ws_b = (const float*)d_in[5];
    const float* We_w = (const float*)d_in[6];
    const float* We_b = (const float*)d_in[7];
    float* out = (float*)d_out;

    char* ws = (char*)d_ws;
    unsigned short* Hs   = (unsigned short*)(ws);                    // 2 MB
    unsigned short* He   = (unsigned short*)(ws + (2ull << 20));     // 2 MB
    unsigned short* Ut   = (unsigned short*)(ws + (4ull << 20));     // 4 MB
    float* linS          = (float*)(ws + (8ull << 20));              // 0.5 MB
    float* linE          = (float*)(ws + (8ull << 20) + (1ull << 19));
    unsigned short* seqb = (unsigned short*)(ws + (9ull << 20));     // 6 MB
    unsigned short* Wcat = (unsigned short*)(ws + (15ull << 20));    // 0.75 MB
    unsigned short* T    = (unsigned short*)(ws + (16ull << 20));    // 64 MB

    kp_conv<<<3456, 256, 0, stream>>>(seq, Ws_w, We_w, seqb, Wcat);
    k0_ut<<<dim3(256, 8), dim3(32, 8), 0, stream>>>(U, Ut);
    k1_hs_he<<<512, 256, 0, stream>>>(seqb, Wcat, Ws_b, We_b, Hs, He);
    k2_lin<<<1024, 256, 0, stream>>>(Hs, He, W_w, W_b, linS, linE);
    k3_T<<<2048, 256, 0, stream>>>(Hs, Ut, T);
    k4_out<<<1024, 256, 0, stream>>>(T, He, linS, linE, out);
}